// Round 8
// baseline (71.877 us; speedup 1.0000x reference)
//
#include <hip/hip_runtime.h>
#include <stdint.h>

#define B_   32
#define L_   8192
#define D_   128
#define KTOP 512
#define NBINS 4096
#define CAP  1024   // candidate capacity (sel[] size)

typedef float v4f __attribute__((ext_vector_type(4)));

// ---------------- Threefry-2x32, key = (0, 42), 20 rounds ----------------
// jax.random.key(42) -> key pair (0, 42); threefry_partitionable 32-bit path:
// bits(p) = x0 ^ x1 of block (hi=0, lo=p).
__device__ __forceinline__ uint32_t rotl32(uint32_t x, int d) {
    return (x << d) | (x >> (32 - d));
}

__device__ __forceinline__ uint32_t threefry_bits(uint32_t p) {
    const uint32_t k0 = 0u, k1 = 42u;
    const uint32_t k2 = 0x1BD11BDAu ^ k0 ^ k1;
    uint32_t x0 = 0u + k0;   // c0 + ks0
    uint32_t x1 = p + k1;    // c1 + ks1
#define TF_R(r) { x0 += x1; x1 = rotl32(x1, r); x1 ^= x0; }
    TF_R(13) TF_R(15) TF_R(26) TF_R(6)   x0 += k1; x1 += k2 + 1u;
    TF_R(17) TF_R(29) TF_R(16) TF_R(24)  x0 += k2; x1 += k0 + 2u;
    TF_R(13) TF_R(15) TF_R(26) TF_R(6)   x0 += k0; x1 += k1 + 3u;
    TF_R(17) TF_R(29) TF_R(16) TF_R(24)  x0 += k1; x1 += k2 + 4u;
    TF_R(13) TF_R(15) TF_R(26) TF_R(6)   x0 += k2; x1 += k0 + 5u;
#undef TF_R
    return x0 ^ x1;
}

// Fused: every block streams 16 KB of zeros into out (validated pattern);
// the first 1024 blocks ALSO compute 256 packed sort keys each (full-chip
// keygen rides under the store stream) and write them to ws.
__global__ __launch_bounds__(256) void zero_keys_kernel(
        const float* __restrict__ probs, const float* __restrict__ mask,
        float* __restrict__ out, uint64_t* __restrict__ keys) {
    const uint32_t blk = blockIdx.x;
    v4f* o = (v4f*)out;
    const uint32_t base = blk * 1024u + threadIdx.x;
    const v4f z = {0.f, 0.f, 0.f, 0.f};
    o[base]       = z;
    o[base + 256] = z;
    o[base + 512] = z;
    o[base + 768] = z;

    if (blk < 1024u) {
        const uint32_t e = blk * 256u + threadIdx.x;   // flat index, 0..262143
        const uint32_t l = e & (L_ - 1u);
        const uint32_t bits = threefry_bits(e);
        const float U = __uint_as_float((bits >> 9) | 0x3F800000u) - 1.0f;
        const float g = -logf(-logf(U + 1e-20f) + 1e-20f);
        const float y = probs[e] / 0.1f + g + mask[e] * (-10000.0f);
        const uint32_t u = __float_as_uint(y);
        const uint32_t mono = u ^ ((u & 0x80000000u) ? 0xFFFFFFFFu : 0x80000000u);
        keys[e] = ((uint64_t)mono << 16) | (uint32_t)(8191u - l);
    }
}

// One block per batch row; keys preloaded from ws. ONE 12-bit histogram +
// suffix scan (refine loop for rare ties). Rank = above[bin] (from the scan)
// + intra-bin scan over ~2 elems -- no O(nc^2) loop.
__global__ __launch_bounds__(1024) void select_kernel(
        const uint64_t* __restrict__ keys,
        float* __restrict__ out_ind, int* __restrict__ ind_i32) {
    const int b    = blockIdx.x;
    const int tid  = threadIdx.x;
    const int lane = tid & 63;
    const int wid  = tid >> 6;

    __shared__ uint32_t hist[NBINS];    // 16 KB; reused as per-bin cursor
    __shared__ uint32_t above[NBINS];   // 16 KB; exclusive suffix counts
    __shared__ uint64_t sel[CAP];       // 8 KB; candidates grouped by bin
    __shared__ uint32_t wtot[16];
    __shared__ uint32_t s_bin, s_above, s_candv;

    uint64_t K[8];
#pragma unroll
    for (int j = 0; j < 8; ++j)
        K[j] = keys[b * L_ + j * 1024 + tid];

    // ---- threshold search: 12-bit digits; level 0 also records above[] ----
    uint64_t prefix = 0;
    uint32_t needed = KTOP;
    uint64_t thrlo  = 0;
    for (int level = 0; level < 4; ++level) {
        const int shift = 36 - level * 12;
        for (int i = tid; i < NBINS; i += 1024) hist[i] = 0u;
        __syncthreads();
#pragma unroll
        for (int j = 0; j < 8; ++j) {
            const bool match = (level == 0) || ((K[j] >> (shift + 12)) == prefix);
            if (match) atomicAdd(&hist[(uint32_t)(K[j] >> shift) & (NBINS - 1u)], 1u);
        }
        __syncthreads();

        // suffix scan: thread t owns bins 4t..4t+3
        const uint32_t h0 = hist[4 * tid + 0];
        const uint32_t h1 = hist[4 * tid + 1];
        const uint32_t h2 = hist[4 * tid + 2];
        const uint32_t h3 = hist[4 * tid + 3];
        const uint32_t ls = h0 + h1 + h2 + h3;
        uint32_t s = ls;
#pragma unroll
        for (int off = 1; off < 64; off <<= 1) {
            const uint32_t v = __shfl_down(s, off);
            if (lane + off < 64) s += v;
        }
        if (lane == 0) wtot[wid] = s;      // whole-wave sum
        __syncthreads();
        uint32_t after_waves = 0;
        for (int w = wid + 1; w < 16; ++w) after_waves += wtot[w];
        const uint32_t base = after_waves + (s - ls);  // sum of bins after my 4
        const uint32_t s3 = h3 + base;
        const uint32_t s2 = h2 + s3;
        const uint32_t s1 = h1 + s2;
        const uint32_t s0 = h0 + s1;
        if (level == 0) {   // exclusive suffix counts = rank bases
            above[4 * tid + 0] = s1;
            above[4 * tid + 1] = s2;
            above[4 * tid + 2] = s3;
            above[4 * tid + 3] = base;
        }
        if (s0 >= needed && s1 < needed)  { s_bin = 4u*tid+0u; s_above = s1;  s_candv = s0; }
        if (s1 >= needed && s2 < needed)  { s_bin = 4u*tid+1u; s_above = s2;  s_candv = s1; }
        if (s2 >= needed && s3 < needed)  { s_bin = 4u*tid+2u; s_above = s3;  s_candv = s2; }
        if (s3 >= needed && base < needed){ s_bin = 4u*tid+3u; s_above = base;s_candv = s3; }
        __syncthreads();

        const uint32_t T = s_bin;
        thrlo = ((prefix << 12) | T) << shift;          // conservative threshold
        const uint32_t G = s_candv + (KTOP - needed);   // global candidate count
        if (G <= CAP) break;                            // ~always at level 0
        prefix = (prefix << 12) | T;
        needed -= s_above;
        __syncthreads();
    }

    // ---- place candidates grouped by level-0 bin: slot = above[bin]+cursor ----
    for (int i = tid; i < NBINS; i += 1024) hist[i] = 0u;   // hist -> cursor
    __syncthreads();
#pragma unroll
    for (int j = 0; j < 8; ++j) {
        if (K[j] >= thrlo) {
            const uint32_t bin = (uint32_t)(K[j] >> 36);
            const uint32_t slot = above[bin] + atomicAdd(&hist[bin], 1u);
            sel[slot] = K[j];
        }
    }
    __syncthreads();

    // ---- exact rank = above[bin] + #{same-bin candidates with larger key} ----
#pragma unroll
    for (int j = 0; j < 8; ++j) {
        if (K[j] >= thrlo) {
            const uint64_t mine = K[j];
            const uint32_t bin  = (uint32_t)(mine >> 36);
            const uint32_t rb   = above[bin];
            const uint32_t cnt  = hist[bin];   // candidates in this bin
            uint32_t r = rb;
            for (uint32_t k = 0; k < cnt; ++k) r += (uint32_t)(sel[rb + k] > mine);
            if (r < KTOP) {
                const uint32_t idx = 8191u - (uint32_t)(mine & 0xFFFFu);
                out_ind[b * KTOP + r] = (float)idx;
                ind_i32[b * KTOP + r] = (int)idx;
            }
        }
    }
}

// Copies the 512 selected rows per batch from reps over the zeros.
// Block = 256 threads = 8 rows (32 lanes/row, one v4f each).
__global__ __launch_bounds__(256) void copy_kernel(
        const float* __restrict__ reps, const int* __restrict__ ind_i32,
        float* __restrict__ out) {
    const int b     = blockIdx.x >> 6;          // 64 blocks per batch
    const int group = blockIdx.x & 63;
    const int r     = group * 8 + (threadIdx.x >> 5);
    const int t     = threadIdx.x & 31;
    const int idx   = ind_i32[b * KTOP + r];
    const size_t off = ((size_t)b * L_ + idx) * D_ + (size_t)t * 4;
    *(v4f*)(out + off) = *(const v4f*)(reps + off);
}

extern "C" void kernel_launch(void* const* d_in, const int* in_sizes, int n_in,
                              void* d_out, int out_size, void* d_ws, size_t ws_size,
                              hipStream_t stream) {
    const float* reps  = (const float*)d_in[0];
    const float* probs = (const float*)d_in[1];
    const float* mask  = (const float*)d_in[2];
    float* out     = (float*)d_out;
    float* out_ind = out + (size_t)B_ * L_ * D_;
    uint64_t* keys = (uint64_t*)d_ws;                    // 2 MB
    int* ind_i32   = (int*)((char*)d_ws + (size_t)B_ * L_ * 8);  // 64 KB after

    hipLaunchKernelGGL(zero_keys_kernel, dim3((B_ * L_ * D_ / 4) / 1024),
                       dim3(256), 0, stream, probs, mask, out, keys);
    hipLaunchKernelGGL(select_kernel, dim3(B_), dim3(1024), 0, stream,
                       keys, out_ind, ind_i32);
    hipLaunchKernelGGL(copy_kernel, dim3(B_ * (KTOP / 8)), dim3(256), 0, stream,
                       reps, ind_i32, out);
}

// Round 10
// 50.818 us; speedup vs baseline: 1.4144x; 1.4144x over previous
//
#include <hip/hip_runtime.h>
#include <stdint.h>

#define B_   32
#define L_   8192
#define D_   128
#define KTOP 512
#define NBINS 4096
#define CAP  1024   // candidate capacity (sel[] size)

typedef float v4f __attribute__((ext_vector_type(4)));

// ---------------- Threefry-2x32, key = (0, 42), 20 rounds ----------------
// jax.random.key(42) -> key pair (0, 42); threefry_partitionable 32-bit path:
// bits(p) = x0 ^ x1 of block (hi=0, lo=p).
__device__ __forceinline__ uint32_t rotl32(uint32_t x, int d) {
    return (x << d) | (x >> (32 - d));
}

__device__ __forceinline__ uint32_t threefry_bits(uint32_t p) {
    const uint32_t k0 = 0u, k1 = 42u;
    const uint32_t k2 = 0x1BD11BDAu ^ k0 ^ k1;
    uint32_t x0 = 0u + k0;   // c0 + ks0
    uint32_t x1 = p + k1;    // c1 + ks1
#define TF_R(r) { x0 += x1; x1 = rotl32(x1, r); x1 ^= x0; }
    TF_R(13) TF_R(15) TF_R(26) TF_R(6)   x0 += k1; x1 += k2 + 1u;
    TF_R(17) TF_R(29) TF_R(16) TF_R(24)  x0 += k2; x1 += k0 + 2u;
    TF_R(13) TF_R(15) TF_R(26) TF_R(6)   x0 += k0; x1 += k1 + 3u;
    TF_R(17) TF_R(29) TF_R(16) TF_R(24)  x0 += k1; x1 += k2 + 4u;
    TF_R(13) TF_R(15) TF_R(26) TF_R(6)   x0 += k2; x1 += k0 + 5u;
#undef TF_R
    return x0 ^ x1;
}

// Fused: every block streams 16 KB of zeros into out (validated pattern);
// the first 1024 blocks ALSO compute 256 packed sort keys each (full-chip
// keygen rides under the store stream) and write them to ws.
__global__ __launch_bounds__(256) void zero_keys_kernel(
        const float* __restrict__ probs, const float* __restrict__ mask,
        float* __restrict__ out, uint64_t* __restrict__ keys) {
    const uint32_t blk = blockIdx.x;
    v4f* o = (v4f*)out;
    const uint32_t base = blk * 1024u + threadIdx.x;
    const v4f z = {0.f, 0.f, 0.f, 0.f};
    o[base]       = z;
    o[base + 256] = z;
    o[base + 512] = z;
    o[base + 768] = z;

    if (blk < 1024u) {
        const uint32_t e = blk * 256u + threadIdx.x;   // flat index, 0..262143
        const uint32_t l = e & (L_ - 1u);
        const uint32_t bits = threefry_bits(e);
        const float U = __uint_as_float((bits >> 9) | 0x3F800000u) - 1.0f;
        const float g = -logf(-logf(U + 1e-20f) + 1e-20f);
        const float y = probs[e] / 0.1f + g + mask[e] * (-10000.0f);
        const uint32_t u = __float_as_uint(y);
        const uint32_t mono = u ^ ((u & 0x80000000u) ? 0xFFFFFFFFu : 0x80000000u);
        keys[e] = ((uint64_t)mono << 16) | (uint32_t)(8191u - l);
    }
}

// One block per batch row (R7-validated structure), keys preloaded from ws.
// 12-bit histogram + suffix scan (refine loop for pathological ties) ->
// compact -> rank-by-counting. The rank inner loop uses v_readlane register
// broadcasts (VALU) instead of LDS broadcast reads: each wave preloads 64
// candidates into registers (10 LDS reads total) and counts via compares.
__global__ __launch_bounds__(1024) void select_kernel(
        const uint64_t* __restrict__ keys,
        float* __restrict__ out_ind, int* __restrict__ ind_i32) {
    const int b    = blockIdx.x;
    const int tid  = threadIdx.x;
    const int lane = tid & 63;
    const int wid  = tid >> 6;

    __shared__ uint32_t hist[NBINS];       // 16 KB
    __shared__ uint64_t sel[CAP];          // 8 KB
    __shared__ uint32_t wtot[16];
    __shared__ uint32_t s_bin, s_above, s_candv, s_cnt;

    uint64_t K[8];
#pragma unroll
    for (int j = 0; j < 8; ++j)
        K[j] = keys[b * L_ + j * 1024 + tid];

    // ---- threshold search: 12-bit digits, usually exits after level 0 ----
    uint64_t prefix = 0;
    uint32_t needed = KTOP;
    uint64_t thrlo  = 0;
    for (int level = 0; level < 4; ++level) {
        const int shift = 36 - level * 12;
        for (int i = tid; i < NBINS; i += 1024) hist[i] = 0u;
        __syncthreads();
#pragma unroll
        for (int j = 0; j < 8; ++j) {
            const bool match = (level == 0) || ((K[j] >> (shift + 12)) == prefix);
            if (match) atomicAdd(&hist[(uint32_t)(K[j] >> shift) & (NBINS - 1u)], 1u);
        }
        __syncthreads();

        // suffix scan: thread t owns bins 4t..4t+3
        const uint32_t h0 = hist[4 * tid + 0];
        const uint32_t h1 = hist[4 * tid + 1];
        const uint32_t h2 = hist[4 * tid + 2];
        const uint32_t h3 = hist[4 * tid + 3];
        const uint32_t ls = h0 + h1 + h2 + h3;
        uint32_t s = ls;
#pragma unroll
        for (int off = 1; off < 64; off <<= 1) {
            const uint32_t v = __shfl_down(s, off);
            if (lane + off < 64) s += v;
        }
        if (lane == 0) wtot[wid] = s;      // whole-wave sum
        __syncthreads();
        uint32_t after_waves = 0;
        for (int w = wid + 1; w < 16; ++w) after_waves += wtot[w];
        const uint32_t base = after_waves + (s - ls);  // sum of bins after my 4
        const uint32_t s3 = h3 + base;
        const uint32_t s2 = h2 + s3;
        const uint32_t s1 = h1 + s2;
        const uint32_t s0 = h0 + s1;
        if (s0 >= needed && s1 < needed)  { s_bin = 4u*tid+0u; s_above = s1;  s_candv = s0; }
        if (s1 >= needed && s2 < needed)  { s_bin = 4u*tid+1u; s_above = s2;  s_candv = s1; }
        if (s2 >= needed && s3 < needed)  { s_bin = 4u*tid+2u; s_above = s3;  s_candv = s2; }
        if (s3 >= needed && base < needed){ s_bin = 4u*tid+3u; s_above = base;s_candv = s3; }
        __syncthreads();

        const uint32_t T = s_bin;
        thrlo = ((prefix << 12) | T) << shift;          // conservative threshold
        const uint32_t G = s_candv + (KTOP - needed);   // global candidate count
        if (G <= CAP) break;                            // ~always at level 0
        prefix = (prefix << 12) | T;
        needed -= s_above;
        __syncthreads();
    }

    // ---- compact candidates (keys >= thrlo) ----
    if (tid == 0) s_cnt = 0u;
    __syncthreads();
#pragma unroll
    for (int j = 0; j < 8; ++j) {
        if (K[j] >= thrlo) {
            const uint32_t pos = atomicAdd(&s_cnt, 1u);
            if (pos < CAP) sel[pos] = K[j];
        }
    }
    __syncthreads();
    const uint32_t nc = s_cnt < CAP ? s_cnt : CAP;

    // ---- rank-by-counting with v_readlane broadcasts (off the LDS pipe) ----
    // Wave-uniform guard: every lane of a participating wave executes the
    // chunk loads, so readlane sources are always defined.
    if ((uint32_t)(wid * 64) < nc) {
        const uint64_t mine = (tid < (int)nc) ? sel[tid] : ~0ull;
        uint32_t r = 0;
        const int nch = ((int)nc + 63) >> 6;
        for (int c = 0; c < nch; ++c) {
            const int idx2 = (c << 6) + lane;
            const uint64_t mykey = (idx2 < (int)nc) ? sel[idx2] : 0ull;
            const uint32_t klo = (uint32_t)mykey;
            const uint32_t khi = (uint32_t)(mykey >> 32);
#pragma unroll
            for (int l = 0; l < 64; ++l) {
                const uint32_t blo = __builtin_amdgcn_readlane(klo, l);
                const uint32_t bhi = __builtin_amdgcn_readlane(khi, l);
                const uint64_t bv = ((uint64_t)bhi << 32) | (uint64_t)blo;
                r += (uint32_t)(bv > mine);
            }
        }
        if (tid < (int)nc && r < KTOP) {
            const uint32_t idx = 8191u - (uint32_t)(mine & 0xFFFFu);
            out_ind[b * KTOP + r] = (float)idx;
            ind_i32[b * KTOP + r] = (int)idx;
        }
    }
}

// Copies the 512 selected rows per batch from reps over the zeros.
// Block = 256 threads = 8 rows (32 lanes/row, one v4f each).
__global__ __launch_bounds__(256) void copy_kernel(
        const float* __restrict__ reps, const int* __restrict__ ind_i32,
        float* __restrict__ out) {
    const int b     = blockIdx.x >> 6;          // 64 blocks per batch
    const int group = blockIdx.x & 63;
    const int r     = group * 8 + (threadIdx.x >> 5);
    const int t     = threadIdx.x & 31;
    const int idx   = ind_i32[b * KTOP + r];
    const size_t off = ((size_t)b * L_ + idx) * D_ + (size_t)t * 4;
    *(v4f*)(out + off) = *(const v4f*)(reps + off);
}

extern "C" void kernel_launch(void* const* d_in, const int* in_sizes, int n_in,
                              void* d_out, int out_size, void* d_ws, size_t ws_size,
                              hipStream_t stream) {
    const float* reps  = (const float*)d_in[0];
    const float* probs = (const float*)d_in[1];
    const float* mask  = (const float*)d_in[2];
    float* out     = (float*)d_out;
    float* out_ind = out + (size_t)B_ * L_ * D_;
    uint64_t* keys = (uint64_t*)d_ws;                    // 2 MB
    int* ind_i32   = (int*)((char*)d_ws + (size_t)B_ * L_ * 8);  // 64 KB after

    hipLaunchKernelGGL(zero_keys_kernel, dim3((B_ * L_ * D_ / 4) / 1024),
                       dim3(256), 0, stream, probs, mask, out, keys);
    hipLaunchKernelGGL(select_kernel, dim3(B_), dim3(1024), 0, stream,
                       keys, out_ind, ind_i32);
    hipLaunchKernelGGL(copy_kernel, dim3(B_ * (KTOP / 8)), dim3(256), 0, stream,
                       reps, ind_i32, out);
}

// Round 11
// 50.324 us; speedup vs baseline: 1.4283x; 1.0098x over previous
//
#include <hip/hip_runtime.h>
#include <stdint.h>

#define B_   32
#define L_   8192
#define D_   128
#define KTOP 512
#define NBINS 4096
#define CAP  1024   // candidate capacity per row

typedef float v4f __attribute__((ext_vector_type(4)));

// ---------------- Threefry-2x32, key = (0, 42), 20 rounds ----------------
__device__ __forceinline__ uint32_t rotl32(uint32_t x, int d) {
    return (x << d) | (x >> (32 - d));
}

__device__ __forceinline__ uint32_t threefry_bits(uint32_t p) {
    const uint32_t k0 = 0u, k1 = 42u;
    const uint32_t k2 = 0x1BD11BDAu ^ k0 ^ k1;
    uint32_t x0 = 0u + k0;
    uint32_t x1 = p + k1;
#define TF_R(r) { x0 += x1; x1 = rotl32(x1, r); x1 ^= x0; }
    TF_R(13) TF_R(15) TF_R(26) TF_R(6)   x0 += k1; x1 += k2 + 1u;
    TF_R(17) TF_R(29) TF_R(16) TF_R(24)  x0 += k2; x1 += k0 + 2u;
    TF_R(13) TF_R(15) TF_R(26) TF_R(6)   x0 += k0; x1 += k1 + 3u;
    TF_R(17) TF_R(29) TF_R(16) TF_R(24)  x0 += k1; x1 += k2 + 4u;
    TF_R(13) TF_R(15) TF_R(26) TF_R(6)   x0 += k2; x1 += k0 + 5u;
#undef TF_R
    return x0 ^ x1;
}

// Fused: every block streams 16 KB of zeros into out (validated pattern);
// the first 1024 blocks ALSO compute 256 packed sort keys each.
__global__ __launch_bounds__(256) void zero_keys_kernel(
        const float* __restrict__ probs, const float* __restrict__ mask,
        float* __restrict__ out, uint64_t* __restrict__ keys) {
    const uint32_t blk = blockIdx.x;
    v4f* o = (v4f*)out;
    const uint32_t base = blk * 1024u + threadIdx.x;
    const v4f z = {0.f, 0.f, 0.f, 0.f};
    o[base]       = z;
    o[base + 256] = z;
    o[base + 512] = z;
    o[base + 768] = z;

    if (blk < 1024u) {
        const uint32_t e = blk * 256u + threadIdx.x;   // flat index, 0..262143
        const uint32_t l = e & (L_ - 1u);
        const uint32_t bits = threefry_bits(e);
        const float U = __uint_as_float((bits >> 9) | 0x3F800000u) - 1.0f;
        const float g = -logf(-logf(U + 1e-20f) + 1e-20f);
        const float y = probs[e] / 0.1f + g + mask[e] * (-10000.0f);
        const uint32_t u = __float_as_uint(y);
        const uint32_t mono = u ^ ((u & 0x80000000u) ? 0xFFFFFFFFu : 0x80000000u);
        keys[e] = ((uint64_t)mono << 16) | (uint32_t)(8191u - l);
    }
}

// One block per batch row: histogram + threshold + compact candidates to
// GLOBAL buffer + nc[b]. No ranking here (that runs full-chip in rank_kernel).
__global__ __launch_bounds__(1024) void select_kernel(
        const uint64_t* __restrict__ keys, uint64_t* __restrict__ cand,
        uint32_t* __restrict__ ncArr) {
    const int b    = blockIdx.x;
    const int tid  = threadIdx.x;
    const int lane = tid & 63;
    const int wid  = tid >> 6;

    __shared__ uint32_t hist[NBINS];       // 16 KB
    __shared__ uint32_t wtot[16];
    __shared__ uint32_t s_bin, s_above, s_candv, s_cnt;

    uint64_t K[8];
#pragma unroll
    for (int j = 0; j < 8; ++j)
        K[j] = keys[b * L_ + j * 1024 + tid];

    // ---- threshold search: 12-bit digits, usually exits after level 0 ----
    uint64_t prefix = 0;
    uint32_t needed = KTOP;
    uint64_t thrlo  = 0;
    for (int level = 0; level < 4; ++level) {
        const int shift = 36 - level * 12;
        for (int i = tid; i < NBINS; i += 1024) hist[i] = 0u;
        __syncthreads();
#pragma unroll
        for (int j = 0; j < 8; ++j) {
            const bool match = (level == 0) || ((K[j] >> (shift + 12)) == prefix);
            if (match) atomicAdd(&hist[(uint32_t)(K[j] >> shift) & (NBINS - 1u)], 1u);
        }
        __syncthreads();

        const uint32_t h0 = hist[4 * tid + 0];
        const uint32_t h1 = hist[4 * tid + 1];
        const uint32_t h2 = hist[4 * tid + 2];
        const uint32_t h3 = hist[4 * tid + 3];
        const uint32_t ls = h0 + h1 + h2 + h3;
        uint32_t s = ls;
#pragma unroll
        for (int off = 1; off < 64; off <<= 1) {
            const uint32_t v = __shfl_down(s, off);
            if (lane + off < 64) s += v;
        }
        if (lane == 0) wtot[wid] = s;
        __syncthreads();
        uint32_t after_waves = 0;
        for (int w = wid + 1; w < 16; ++w) after_waves += wtot[w];
        const uint32_t base = after_waves + (s - ls);
        const uint32_t s3 = h3 + base;
        const uint32_t s2 = h2 + s3;
        const uint32_t s1 = h1 + s2;
        const uint32_t s0 = h0 + s1;
        if (s0 >= needed && s1 < needed)  { s_bin = 4u*tid+0u; s_above = s1;  s_candv = s0; }
        if (s1 >= needed && s2 < needed)  { s_bin = 4u*tid+1u; s_above = s2;  s_candv = s1; }
        if (s2 >= needed && s3 < needed)  { s_bin = 4u*tid+2u; s_above = s3;  s_candv = s2; }
        if (s3 >= needed && base < needed){ s_bin = 4u*tid+3u; s_above = base;s_candv = s3; }
        __syncthreads();

        const uint32_t T = s_bin;
        thrlo = ((prefix << 12) | T) << shift;
        const uint32_t G = s_candv + (KTOP - needed);
        if (G <= CAP) break;
        prefix = (prefix << 12) | T;
        needed -= s_above;
        __syncthreads();
    }

    // ---- compact candidates (keys >= thrlo) to global ----
    if (tid == 0) s_cnt = 0u;
    __syncthreads();
#pragma unroll
    for (int j = 0; j < 8; ++j) {
        if (K[j] >= thrlo) {
            const uint32_t pos = atomicAdd(&s_cnt, 1u);
            if (pos < CAP) cand[b * CAP + pos] = K[j];
        }
    }
    __syncthreads();
    if (tid == 0) ncArr[b] = s_cnt < CAP ? s_cnt : CAP;
}

// Full-chip flat rank: 16 blocks x 64 threads per row; block stages the row's
// candidates in LDS, each thread ranks ONE candidate by counting larger keys.
__global__ __launch_bounds__(64) void rank_kernel(
        const uint64_t* __restrict__ cand, const uint32_t* __restrict__ ncArr,
        float* __restrict__ out_ind, int* __restrict__ ind_i32) {
    const int b    = blockIdx.x >> 4;
    const int g    = blockIdx.x & 15;
    const int lane = threadIdx.x;

    __shared__ uint64_t sc[CAP];   // 8 KB
    const uint32_t nc = ncArr[b];
    if ((uint32_t)(g * 64) >= nc) return;

    for (uint32_t i = lane; i < nc; i += 64) sc[i] = cand[b * CAP + i];
    __syncthreads();

    const uint32_t ci = (uint32_t)(g * 64 + lane);
    const uint64_t mine = ci < nc ? sc[ci] : ~0ull;
    uint32_t r = 0;
    uint32_t k = 0;
    for (; k + 4 <= nc; k += 4) {
        r += (uint32_t)(sc[k]     > mine);
        r += (uint32_t)(sc[k + 1] > mine);
        r += (uint32_t)(sc[k + 2] > mine);
        r += (uint32_t)(sc[k + 3] > mine);
    }
    for (; k < nc; ++k) r += (uint32_t)(sc[k] > mine);

    if (ci < nc && r < KTOP) {
        const uint32_t idx = 8191u - (uint32_t)(mine & 0xFFFFu);
        out_ind[b * KTOP + r] = (float)idx;
        ind_i32[b * KTOP + r] = (int)idx;
    }
}

// Copies the 512 selected rows per batch from reps over the zeros.
__global__ __launch_bounds__(256) void copy_kernel(
        const float* __restrict__ reps, const int* __restrict__ ind_i32,
        float* __restrict__ out) {
    const int b     = blockIdx.x >> 6;          // 64 blocks per batch
    const int group = blockIdx.x & 63;
    const int r     = group * 8 + (threadIdx.x >> 5);
    const int t     = threadIdx.x & 31;
    const int idx   = ind_i32[b * KTOP + r];
    const size_t off = ((size_t)b * L_ + idx) * D_ + (size_t)t * 4;
    *(v4f*)(out + off) = *(const v4f*)(reps + off);
}

extern "C" void kernel_launch(void* const* d_in, const int* in_sizes, int n_in,
                              void* d_out, int out_size, void* d_ws, size_t ws_size,
                              hipStream_t stream) {
    const float* reps  = (const float*)d_in[0];
    const float* probs = (const float*)d_in[1];
    const float* mask  = (const float*)d_in[2];
    float* out     = (float*)d_out;
    float* out_ind = out + (size_t)B_ * L_ * D_;

    char* ws = (char*)d_ws;
    uint64_t* keys  = (uint64_t*)ws;                               // 2 MB
    uint64_t* cand  = (uint64_t*)(ws + (size_t)B_ * L_ * 8);       // 256 KB
    uint32_t* ncArr = (uint32_t*)(ws + (size_t)B_ * L_ * 8 + (size_t)B_ * CAP * 8);
    int* ind_i32    = (int*)(ws + (size_t)B_ * L_ * 8 + (size_t)B_ * CAP * 8 + 1024);

    hipLaunchKernelGGL(zero_keys_kernel, dim3((B_ * L_ * D_ / 4) / 1024),
                       dim3(256), 0, stream, probs, mask, out, keys);
    hipLaunchKernelGGL(select_kernel, dim3(B_), dim3(1024), 0, stream,
                       keys, cand, ncArr);
    hipLaunchKernelGGL(rank_kernel, dim3(B_ * 16), dim3(64), 0, stream,
                       cand, ncArr, out_ind, ind_i32);
    hipLaunchKernelGGL(copy_kernel, dim3(B_ * (KTOP / 8)), dim3(256), 0, stream,
                       reps, ind_i32, out);
}

// Round 12
// 45.870 us; speedup vs baseline: 1.5670x; 1.0971x over previous
//
#include <hip/hip_runtime.h>
#include <stdint.h>

#define B_   32
#define L_   8192
#define D_   128
#define KTOP 512
#define NBINS 4096
#define CAP  1024   // candidate capacity (sel[] size)

typedef float v4f __attribute__((ext_vector_type(4)));
typedef unsigned long long v2u64 __attribute__((ext_vector_type(2)));

// ---------------- Threefry-2x32, key = (0, 42), 20 rounds ----------------
// jax.random.key(42) -> key pair (0, 42); threefry_partitionable 32-bit path:
// bits(p) = x0 ^ x1 of block (hi=0, lo=p).
__device__ __forceinline__ uint32_t rotl32(uint32_t x, int d) {
    return (x << d) | (x >> (32 - d));
}

__device__ __forceinline__ uint32_t threefry_bits(uint32_t p) {
    const uint32_t k0 = 0u, k1 = 42u;
    const uint32_t k2 = 0x1BD11BDAu ^ k0 ^ k1;
    uint32_t x0 = 0u + k0;   // c0 + ks0
    uint32_t x1 = p + k1;    // c1 + ks1
#define TF_R(r) { x0 += x1; x1 = rotl32(x1, r); x1 ^= x0; }
    TF_R(13) TF_R(15) TF_R(26) TF_R(6)   x0 += k1; x1 += k2 + 1u;
    TF_R(17) TF_R(29) TF_R(16) TF_R(24)  x0 += k2; x1 += k0 + 2u;
    TF_R(13) TF_R(15) TF_R(26) TF_R(6)   x0 += k0; x1 += k1 + 3u;
    TF_R(17) TF_R(29) TF_R(16) TF_R(24)  x0 += k1; x1 += k2 + 4u;
    TF_R(13) TF_R(15) TF_R(26) TF_R(6)   x0 += k2; x1 += k0 + 5u;
#undef TF_R
    return x0 ^ x1;
}

// Fused: every block streams 16 KB of zeros into out (validated pattern);
// the first 1024 blocks ALSO compute 256 packed sort keys each (full-chip
// keygen rides under the store stream) and write them to ws.
__global__ __launch_bounds__(256) void zero_keys_kernel(
        const float* __restrict__ probs, const float* __restrict__ mask,
        float* __restrict__ out, uint64_t* __restrict__ keys) {
    const uint32_t blk = blockIdx.x;
    v4f* o = (v4f*)out;
    const uint32_t base = blk * 1024u + threadIdx.x;
    const v4f z = {0.f, 0.f, 0.f, 0.f};
    o[base]       = z;
    o[base + 256] = z;
    o[base + 512] = z;
    o[base + 768] = z;

    if (blk < 1024u) {
        const uint32_t e = blk * 256u + threadIdx.x;   // flat index, 0..262143
        const uint32_t l = e & (L_ - 1u);
        const uint32_t bits = threefry_bits(e);
        const float U = __uint_as_float((bits >> 9) | 0x3F800000u) - 1.0f;
        const float g = -logf(-logf(U + 1e-20f) + 1e-20f);
        const float y = probs[e] / 0.1f + g + mask[e] * (-10000.0f);
        const uint32_t u = __float_as_uint(y);
        const uint32_t mono = u ^ ((u & 0x80000000u) ? 0xFFFFFFFFu : 0x80000000u);
        keys[e] = ((uint64_t)mono << 16) | (uint32_t)(8191u - l);
    }
}

// One block per batch row (R7-validated structure), keys preloaded from ws.
// 12-bit histogram + suffix scan (refine loop for pathological ties) ->
// compact -> flat rank-by-counting, with the rank inner loop reading sel[]
// via ds_read_b128 (2 keys per LDS issue) to halve LDS-pipe pressure.
__global__ __launch_bounds__(1024) void select_kernel(
        const uint64_t* __restrict__ keys,
        float* __restrict__ out_ind, int* __restrict__ ind_i32) {
    const int b    = blockIdx.x;
    const int tid  = threadIdx.x;
    const int lane = tid & 63;
    const int wid  = tid >> 6;

    __shared__ uint32_t hist[NBINS];                // 16 KB
    __shared__ __align__(16) uint64_t sel[CAP];     // 8 KB
    __shared__ uint32_t wtot[16];
    __shared__ uint32_t s_bin, s_above, s_candv, s_cnt;

    uint64_t K[8];
#pragma unroll
    for (int j = 0; j < 8; ++j)
        K[j] = keys[b * L_ + j * 1024 + tid];

    // ---- threshold search: 12-bit digits, usually exits after level 0 ----
    uint64_t prefix = 0;
    uint32_t needed = KTOP;
    uint64_t thrlo  = 0;
    for (int level = 0; level < 4; ++level) {
        const int shift = 36 - level * 12;
        for (int i = tid; i < NBINS; i += 1024) hist[i] = 0u;
        __syncthreads();
#pragma unroll
        for (int j = 0; j < 8; ++j) {
            const bool match = (level == 0) || ((K[j] >> (shift + 12)) == prefix);
            if (match) atomicAdd(&hist[(uint32_t)(K[j] >> shift) & (NBINS - 1u)], 1u);
        }
        __syncthreads();

        // suffix scan: thread t owns bins 4t..4t+3
        const uint32_t h0 = hist[4 * tid + 0];
        const uint32_t h1 = hist[4 * tid + 1];
        const uint32_t h2 = hist[4 * tid + 2];
        const uint32_t h3 = hist[4 * tid + 3];
        const uint32_t ls = h0 + h1 + h2 + h3;
        uint32_t s = ls;
#pragma unroll
        for (int off = 1; off < 64; off <<= 1) {
            const uint32_t v = __shfl_down(s, off);
            if (lane + off < 64) s += v;
        }
        if (lane == 0) wtot[wid] = s;      // whole-wave sum
        __syncthreads();
        uint32_t after_waves = 0;
        for (int w = wid + 1; w < 16; ++w) after_waves += wtot[w];
        const uint32_t base = after_waves + (s - ls);  // sum of bins after my 4
        const uint32_t s3 = h3 + base;
        const uint32_t s2 = h2 + s3;
        const uint32_t s1 = h1 + s2;
        const uint32_t s0 = h0 + s1;
        if (s0 >= needed && s1 < needed)  { s_bin = 4u*tid+0u; s_above = s1;  s_candv = s0; }
        if (s1 >= needed && s2 < needed)  { s_bin = 4u*tid+1u; s_above = s2;  s_candv = s1; }
        if (s2 >= needed && s3 < needed)  { s_bin = 4u*tid+2u; s_above = s3;  s_candv = s2; }
        if (s3 >= needed && base < needed){ s_bin = 4u*tid+3u; s_above = base;s_candv = s3; }
        __syncthreads();

        const uint32_t T = s_bin;
        thrlo = ((prefix << 12) | T) << shift;          // conservative threshold
        const uint32_t G = s_candv + (KTOP - needed);   // global candidate count
        if (G <= CAP) break;                            // ~always at level 0
        prefix = (prefix << 12) | T;
        needed -= s_above;
        __syncthreads();
    }

    // ---- compact candidates (keys >= thrlo) ----
    if (tid == 0) s_cnt = 0u;
    __syncthreads();
#pragma unroll
    for (int j = 0; j < 8; ++j) {
        if (K[j] >= thrlo) {
            const uint32_t pos = atomicAdd(&s_cnt, 1u);
            if (pos < CAP) sel[pos] = K[j];
        }
    }
    __syncthreads();
    const uint32_t nc = s_cnt < CAP ? s_cnt : CAP;

    // ---- rank-position via b128 LDS reads: 2 keys per issue, 8 per iter ----
    if (tid < (int)nc) {
        const uint64_t mine = sel[tid];
        const v2u64* s2p = (const v2u64*)sel;
        const uint32_t n2 = nc >> 1;
        uint32_t r = 0;
        uint32_t k = 0;
        for (; k + 4 <= n2; k += 4) {
            const v2u64 a = s2p[k];
            const v2u64 c = s2p[k + 1];
            const v2u64 d = s2p[k + 2];
            const v2u64 e = s2p[k + 3];
            r += (uint32_t)(a[0] > mine) + (uint32_t)(a[1] > mine);
            r += (uint32_t)(c[0] > mine) + (uint32_t)(c[1] > mine);
            r += (uint32_t)(d[0] > mine) + (uint32_t)(d[1] > mine);
            r += (uint32_t)(e[0] > mine) + (uint32_t)(e[1] > mine);
        }
        for (; k < n2; ++k) {
            const v2u64 a = s2p[k];
            r += (uint32_t)(a[0] > mine) + (uint32_t)(a[1] > mine);
        }
        if (nc & 1u) r += (uint32_t)(sel[nc - 1] > mine);
        if (r < KTOP) {
            const uint32_t idx = 8191u - (uint32_t)(mine & 0xFFFFu);
            out_ind[b * KTOP + r] = (float)idx;
            ind_i32[b * KTOP + r] = (int)idx;
        }
    }
}

// Copies the 512 selected rows per batch from reps over the zeros.
// Block = 256 threads = 8 rows (32 lanes/row, one v4f each).
__global__ __launch_bounds__(256) void copy_kernel(
        const float* __restrict__ reps, const int* __restrict__ ind_i32,
        float* __restrict__ out) {
    const int b     = blockIdx.x >> 6;          // 64 blocks per batch
    const int group = blockIdx.x & 63;
    const int r     = group * 8 + (threadIdx.x >> 5);
    const int t     = threadIdx.x & 31;
    const int idx   = ind_i32[b * KTOP + r];
    const size_t off = ((size_t)b * L_ + idx) * D_ + (size_t)t * 4;
    *(v4f*)(out + off) = *(const v4f*)(reps + off);
}

extern "C" void kernel_launch(void* const* d_in, const int* in_sizes, int n_in,
                              void* d_out, int out_size, void* d_ws, size_t ws_size,
                              hipStream_t stream) {
    const float* reps  = (const float*)d_in[0];
    const float* probs = (const float*)d_in[1];
    const float* mask  = (const float*)d_in[2];
    float* out     = (float*)d_out;
    float* out_ind = out + (size_t)B_ * L_ * D_;
    uint64_t* keys = (uint64_t*)d_ws;                    // 2 MB
    int* ind_i32   = (int*)((char*)d_ws + (size_t)B_ * L_ * 8);  // 64 KB after

    hipLaunchKernelGGL(zero_keys_kernel, dim3((B_ * L_ * D_ / 4) / 1024),
                       dim3(256), 0, stream, probs, mask, out, keys);
    hipLaunchKernelGGL(select_kernel, dim3(B_), dim3(1024), 0, stream,
                       keys, out_ind, ind_i32);
    hipLaunchKernelGGL(copy_kernel, dim3(B_ * (KTOP / 8)), dim3(256), 0, stream,
                       reps, ind_i32, out);
}